// Round 1
// baseline (6146.985 us; speedup 1.0000x reference)
//
#include <hip/hip_runtime.h>

#define BB 4
#define NN 8192
#define PP 2048
#define KNB 16
#define CIN 64
#define COUT 128

__device__ __forceinline__ float elu(float x) { return x > 0.0f ? x : expm1f(x); }

// monotone float->uint key (handles negative floats from cancellation)
__device__ __forceinline__ unsigned fkey(float d) {
    unsigned u = __float_as_uint(d);
    unsigned m = (unsigned)((int)u >> 31);
    return u ^ (m | 0x80000000u);
}

// ---------------------------------------------------------------------------
// FPS: one block per batch, 1024 threads, 8 points/thread in registers.
// Exact IEEE ops (no FMA) to match numpy/jax reference selection.
// ---------------------------------------------------------------------------
__global__ __launch_bounds__(1024) void fps_kernel(const float* __restrict__ pts,
                                                   float* __restrict__ rep) {
    const int b = blockIdx.x;
    const int t = threadIdx.x;
    const int lane = t & 63, wave = t >> 6;
    __shared__ float4 part4[2][16];
    __shared__ int    parti[2][16];

    const float* pb = pts + (size_t)b * NN * 3;

    float px[8], py[8], pz[8], dist[8];
    {
        const float4* p4 = (const float4*)(pb + t * 24);
        float v[24];
#pragma unroll
        for (int q = 0; q < 6; ++q) {
            float4 f = p4[q];
            v[q * 4 + 0] = f.x; v[q * 4 + 1] = f.y; v[q * 4 + 2] = f.z; v[q * 4 + 3] = f.w;
        }
#pragma unroll
        for (int r = 0; r < 8; ++r) {
            px[r] = v[r * 3 + 0]; py[r] = v[r * 3 + 1]; pz[r] = v[r * 3 + 2];
            dist[r] = 1e10f;
        }
    }

    float cx = pb[0], cy = pb[1], cz = pb[2];
    if (t == 0) {
        rep[(size_t)b * PP * 3 + 0] = cx;
        rep[(size_t)b * PP * 3 + 1] = cy;
        rep[(size_t)b * PP * 3 + 2] = cz;
    }

    int buf = 0;
    for (int s = 1; s < PP; ++s) {
        float bv = -1.0f; int bi = 0;
        float bx = cx, by = cy, bz = cz;
#pragma unroll
        for (int r = 0; r < 8; ++r) {
            float dx = __fsub_rn(px[r], cx);
            float dy = __fsub_rn(py[r], cy);
            float dz = __fsub_rn(pz[r], cz);
            float d = __fadd_rn(__fadd_rn(__fmul_rn(dx, dx), __fmul_rn(dy, dy)), __fmul_rn(dz, dz));
            float nd = fminf(dist[r], d);
            dist[r] = nd;
            bool tk = nd > bv;   // strict >: first-max within ascending index
            bv = tk ? nd : bv; bi = tk ? (t * 8 + r) : bi;
            bx = tk ? px[r] : bx; by = tk ? py[r] : by; bz = tk ? pz[r] : bz;
        }
        // wave-level lexicographic (max v, min i) butterfly reduce, coords carried
#pragma unroll
        for (int off = 1; off < 64; off <<= 1) {
            float ov = __shfl_xor(bv, off); int oi = __shfl_xor(bi, off);
            float ox = __shfl_xor(bx, off), oy = __shfl_xor(by, off), oz = __shfl_xor(bz, off);
            bool tk = (ov > bv) || (ov == bv && oi < bi);
            bv = tk ? ov : bv; bi = tk ? oi : bi;
            bx = tk ? ox : bx; by = tk ? oy : by; bz = tk ? oz : bz;
        }
        if (lane == 0) {
            part4[buf][wave] = make_float4(bx, by, bz, bv);
            parti[buf][wave] = bi;
        }
        __syncthreads();
        // every thread scans 16 partials (broadcast LDS reads), no 2nd barrier
        float4 w4 = part4[buf][0]; int wi = parti[buf][0];
#pragma unroll
        for (int q = 1; q < 16; ++q) {
            float4 c4 = part4[buf][q]; int ci = parti[buf][q];
            bool tk = (c4.w > w4.w) || (c4.w == w4.w && ci < wi);
            if (tk) { w4 = c4; wi = ci; }
        }
        cx = w4.x; cy = w4.y; cz = w4.z;
        if (t == 0) {
            rep[((size_t)b * PP + s) * 3 + 0] = cx;
            rep[((size_t)b * PP + s) * 3 + 1] = cy;
            rep[((size_t)b * PP + s) * 3 + 2] = cz;
        }
        buf ^= 1;
    }
}

// ---------------------------------------------------------------------------
// Dense: fts_d = elu(fts @ W + b). One wave per row, lane = output channel.
// ---------------------------------------------------------------------------
__global__ __launch_bounds__(256) void dense_kernel(const float* __restrict__ fts,
                                                    const float* __restrict__ W,
                                                    const float* __restrict__ bias,
                                                    float* __restrict__ out) {
    const int row = blockIdx.x * 4 + (threadIdx.x >> 6);
    const int c = threadIdx.x & 63;
    float v = fts[(size_t)row * 64 + c];
    float acc = bias[c];
#pragma unroll 8
    for (int k = 0; k < 64; ++k) acc = fmaf(__shfl(v, k), W[k * 64 + c], acc);
    out[(size_t)row * 64 + c] = elu(acc);
}

// ---------------------------------------------------------------------------
// KNN: one wave per rep point; per-lane sorted top-16 of 128 candidates via
// u64 keys (flipped dist bits << 32 | idx); 16-round lex-min merge-extract.
// Exact IEEE ops, same evaluation order as reference: (a - 2b) + c.
// ---------------------------------------------------------------------------
__global__ __launch_bounds__(256) void knn_kernel(const float* __restrict__ pts,
                                                  const float* __restrict__ rep,
                                                  int* __restrict__ kidx) {
    const int wid = blockIdx.x * 4 + (threadIdx.x >> 6);
    const int lane = threadIdx.x & 63;
    const int b = wid >> 11;
    const float* pb = pts + (size_t)b * NN * 3;

    float rx = rep[(size_t)wid * 3 + 0];
    float ry = rep[(size_t)wid * 3 + 1];
    float rz = rep[(size_t)wid * 3 + 2];
    float a = __fadd_rn(__fadd_rn(__fmul_rn(rx, rx), __fmul_rn(ry, ry)), __fmul_rn(rz, rz));

    unsigned long long key[16];
#pragma unroll
    for (int s = 0; s < 16; ++s) key[s] = ~0ULL;

    for (int j = lane; j < NN; j += 64) {
        float qx = pb[j * 3 + 0], qy = pb[j * 3 + 1], qz = pb[j * 3 + 2];
        float cc = __fadd_rn(__fadd_rn(__fmul_rn(qx, qx), __fmul_rn(qy, qy)), __fmul_rn(qz, qz));
        float bs = __fadd_rn(__fadd_rn(__fmul_rn(rx, qx), __fmul_rn(ry, qy)), __fmul_rn(rz, qz));
        float d2 = __fadd_rn(__fsub_rn(a, __fmul_rn(2.0f, bs)), cc);
        unsigned long long nk = ((unsigned long long)fkey(d2) << 32) | (unsigned)j;
        if (nk < key[15]) {
            key[15] = nk;
#pragma unroll
            for (int s2 = 15; s2 > 0; --s2) {
                unsigned long long u = key[s2 - 1], w = key[s2];
                bool sw = w < u;
                key[s2 - 1] = sw ? w : u;
                key[s2] = sw ? u : w;
            }
        }
    }

    int outv = 0;
#pragma unroll 1
    for (int r = 0; r < 16; ++r) {
        unsigned long long h = key[0];
#pragma unroll
        for (int off = 1; off < 64; off <<= 1) {
            unsigned long long o = __shfl_xor(h, off);
            h = (o < h) ? o : h;
        }
        if (lane == r) outv = (int)(unsigned)(h & 0xFFFFFFFFull);
        if (key[0] == h) {  // unique winner (idx embedded in key)
#pragma unroll
            for (int s2 = 0; s2 < 15; ++s2) key[s2] = key[s2 + 1];
            key[15] = ~0ULL;
        }
    }
    if (lane < 16) kidx[(size_t)wid * 16 + lane] = outv;
}

// ---------------------------------------------------------------------------
// XConv + SepConv: one 64-thread block per rep point, all staged through LDS.
// ---------------------------------------------------------------------------
__global__ __launch_bounds__(64) void xconv_kernel(
    const float* __restrict__ pts, const float* __restrict__ rep,
    const float* __restrict__ ftsd, const int* __restrict__ kidx,
    const float* __restrict__ d1W, const float* __restrict__ d1b,
    const float* __restrict__ d2W, const float* __restrict__ d2b,
    const float* __restrict__ convW, const float* __restrict__ convb,
    const float* __restrict__ dw1W, const float* __restrict__ dw1b,
    const float* __restrict__ dw2W, const float* __restrict__ dw2b,
    const float* __restrict__ sdwW, const float* __restrict__ sdwb,
    const float* __restrict__ spwW, const float* __restrict__ spwb,
    float* __restrict__ outp) {
    const int bp = blockIdx.x;
    const int b = bp >> 11;
    const int t = threadIdx.x;

    __shared__ float pl[16][3];
    __shared__ int nidx[16];
    __shared__ float fcat[16][96];   // cols 0..31 = lift, 32..95 = gathered fts_d
    __shared__ float A1[16][32];
    __shared__ float Xm[16][17];
    __shared__ float X2[16][17];
    __shared__ float X3[16][17];
    __shared__ float fX[16][97];
    __shared__ float dsep[192];

    if (t < 16) {
        int id = kidx[(size_t)bp * 16 + t];
        nidx[t] = id;
        const float* q = pts + ((size_t)b * NN + id) * 3;
        const float* rr = rep + (size_t)bp * 3;
        pl[t][0] = q[0] - rr[0];
        pl[t][1] = q[1] - rr[1];
        pl[t][2] = q[2] - rr[2];
    }
    __syncthreads();

    // gather neighbor features (coalesced: lane = channel)
#pragma unroll
    for (int k = 0; k < 16; ++k)
        fcat[k][32 + t] = ftsd[((size_t)b * NN + nidx[k]) * 64 + t];

    // lift MLP layer 1: [16,3] @ [3,32]
#pragma unroll
    for (int r2 = 0; r2 < 8; ++r2) {
        int e = t + 64 * r2; int k = e >> 5, j = e & 31;
        float acc = d1b[j];
        acc = fmaf(pl[k][0], d1W[j], acc);
        acc = fmaf(pl[k][1], d1W[32 + j], acc);
        acc = fmaf(pl[k][2], d1W[64 + j], acc);
        A1[k][j] = elu(acc);
    }
    __syncthreads();

    // lift MLP layer 2: [16,32] @ [32,32] -> fcat cols 0..31
#pragma unroll
    for (int r2 = 0; r2 < 8; ++r2) {
        int e = t + 64 * r2; int k = e >> 5, j = e & 31;
        float acc = d2b[j];
#pragma unroll
        for (int c = 0; c < 32; ++c) acc = fmaf(A1[k][c], d2W[c * 32 + j], acc);
        fcat[k][j] = elu(acc);
    }
    __syncthreads();

    // X matrix: X[o] = elu(sum_{c,k} pl[k][c]*convW[o][c][k] + convb[o]), o=0..255
#pragma unroll
    for (int r2 = 0; r2 < 4; ++r2) {
        int o = t + 64 * r2;
        float acc = convb[o];
#pragma unroll
        for (int c = 0; c < 3; ++c)
#pragma unroll
            for (int k = 0; k < 16; ++k)
                acc = fmaf(pl[k][c], convW[(o * 3 + c) * 16 + k], acc);
        Xm[o >> 4][o & 15] = elu(acc);
    }
    __syncthreads();

    // dw1: out[j][m] = elu(sum_i Xm[i][j]*dw1W[j][m][i] + dw1b[j][m])
#pragma unroll
    for (int r2 = 0; r2 < 4; ++r2) {
        int e = t + 64 * r2; int j = e >> 4, m = e & 15;
        float acc = dw1b[e];
#pragma unroll
        for (int i = 0; i < 16; ++i) acc = fmaf(Xm[i][j], dw1W[e * 16 + i], acc);
        X2[j][m] = elu(acc);
    }
    __syncthreads();

    // dw2 (no ELU)
#pragma unroll
    for (int r2 = 0; r2 < 4; ++r2) {
        int e = t + 64 * r2; int j = e >> 4, m = e & 15;
        float acc = dw2b[e];
#pragma unroll
        for (int i = 0; i < 16; ++i) acc = fmaf(X2[i][j], dw2W[e * 16 + i], acc);
        X3[j][m] = acc;
    }
    __syncthreads();

    // fts_X[a][c] = sum_b X3[a][b] * fcat[b][c]
#pragma unroll
    for (int r2 = 0; r2 < 24; ++r2) {
        int e = t + 64 * r2; int a = e & 15, c = e >> 4;
        float acc = 0.0f;
#pragma unroll
        for (int q = 0; q < 16; ++q) acc = fmaf(X3[a][q], fcat[q][c], acc);
        fX[a][c] = acc;
    }
    __syncthreads();

    // separable depthwise: d[c][m] = sum_k fX[k][c]*sdwW[c][m][k] + sdwb[c][m]
#pragma unroll
    for (int r2 = 0; r2 < 3; ++r2) {
        int e = t + 64 * r2; int c = e >> 1;
        float acc = sdwb[e];
#pragma unroll
        for (int k = 0; k < 16; ++k) acc = fmaf(fX[k][c], sdwW[e * 16 + k], acc);
        dsep[e] = acc;
    }
    __syncthreads();

    // pointwise: out[o] = elu(sum_{c,m} d[c][m]*spwW[o][c][m] + spwb[o])
#pragma unroll
    for (int r2 = 0; r2 < 2; ++r2) {
        int o = t + 64 * r2;
        float acc = spwb[o];
#pragma unroll 16
        for (int e2 = 0; e2 < 192; ++e2) acc = fmaf(dsep[e2], spwW[o * 192 + e2], acc);
        outp[(size_t)bp * 128 + o] = elu(acc);
    }
}

extern "C" void kernel_launch(void* const* d_in, const int* in_sizes, int n_in,
                              void* d_out, int out_size, void* d_ws, size_t ws_size,
                              hipStream_t stream) {
    const float* pts    = (const float*)d_in[0];
    const float* fts    = (const float*)d_in[1];
    const float* denseW = (const float*)d_in[2];
    const float* denseb = (const float*)d_in[3];
    const float* d1W    = (const float*)d_in[4];
    const float* d1b    = (const float*)d_in[5];
    const float* d2W    = (const float*)d_in[6];
    const float* d2b    = (const float*)d_in[7];
    const float* convW  = (const float*)d_in[8];
    const float* convb  = (const float*)d_in[9];
    const float* dw1W   = (const float*)d_in[10];
    const float* dw1b   = (const float*)d_in[11];
    const float* dw2W   = (const float*)d_in[12];
    const float* dw2b   = (const float*)d_in[13];
    const float* sdwW   = (const float*)d_in[14];
    const float* sdwb   = (const float*)d_in[15];
    const float* spwW   = (const float*)d_in[16];
    const float* spwb   = (const float*)d_in[17];

    float* rep  = (float*)d_out;                       // [B,P,3]
    float* outp = (float*)d_out + (size_t)BB * PP * 3; // [B,P,128]

    float* ftsd = (float*)d_ws;                                            // B*N*64 f32
    int*   kidx = (int*)((char*)d_ws + (size_t)BB * NN * CIN * sizeof(float)); // B*P*16 i32

    dense_kernel<<<BB * NN / 4, 256, 0, stream>>>(fts, denseW, denseb, ftsd);
    fps_kernel<<<BB, 1024, 0, stream>>>(pts, rep);
    knn_kernel<<<BB * PP / 4, 256, 0, stream>>>(pts, rep, kidx);
    xconv_kernel<<<BB * PP, 64, 0, stream>>>(pts, rep, ftsd, kidx,
                                             d1W, d1b, d2W, d2b, convW, convb,
                                             dw1W, dw1b, dw2W, dw2b,
                                             sdwW, sdwb, spwW, spwb, outp);
}

// Round 2
// 2994.602 us; speedup vs baseline: 2.0527x; 2.0527x over previous
//
#include <hip/hip_runtime.h>

#define BB 4
#define NN 8192
#define PP 2048
#define KNB 16
#define CIN 64
#define COUT 128

__device__ __forceinline__ float elu(float x) { return x > 0.0f ? x : expm1f(x); }

// monotone float->uint key (handles negative floats from cancellation)
__device__ __forceinline__ unsigned fkey(float d) {
    unsigned u = __float_as_uint(d);
    unsigned m = (unsigned)((int)u >> 31);
    return u ^ (m | 0x80000000u);
}

// ---------------------------------------------------------------------------
// FPS v2: one block per batch, 1024 threads, 8 points/thread in registers,
// all points mirrored in LDS for winner-coordinate lookup.
// Packed u64 key (dist_bits<<32 | (8191-idx)) -> single max-reduce carries
// value+index+tiebreak; wave0 does the final 16-partial reduce alone.
// Exact IEEE ops (no FMA) in distance path to match reference selection.
// ---------------------------------------------------------------------------
__global__ __launch_bounds__(1024) void fps_kernel(const float* __restrict__ pts,
                                                   float* __restrict__ rep) {
    const int b = blockIdx.x;
    const int t = threadIdx.x;
    const int lane = t & 63, wave = t >> 6;

    __shared__ float spx[NN];
    __shared__ float spy[NN];
    __shared__ float spz[NN];
    __shared__ unsigned long long partk[16];
    __shared__ float4 cres;

    const float* pb = pts + (size_t)b * NN * 3;
    for (int i = t; i < NN; i += 1024) {
        spx[i] = pb[3 * i + 0];
        spy[i] = pb[3 * i + 1];
        spz[i] = pb[3 * i + 2];
    }
    __syncthreads();

    float px[8], py[8], pz[8], dist[8];
#pragma unroll
    for (int r = 0; r < 8; ++r) {
        px[r] = spx[t * 8 + r];
        py[r] = spy[t * 8 + r];
        pz[r] = spz[t * 8 + r];
        dist[r] = 1e10f;
    }

    float cx = spx[0], cy = spy[0], cz = spz[0];
    if (t == 0) {
        rep[(size_t)b * PP * 3 + 0] = cx;
        rep[(size_t)b * PP * 3 + 1] = cy;
        rep[(size_t)b * PP * 3 + 2] = cz;
    }

    for (int s = 1; s < PP; ++s) {
        float bv = -1.0f; int bi = 0;
#pragma unroll
        for (int r = 0; r < 8; ++r) {
            float dx = __fsub_rn(px[r], cx);
            float dy = __fsub_rn(py[r], cy);
            float dz = __fsub_rn(pz[r], cz);
            float d = __fadd_rn(__fadd_rn(__fmul_rn(dx, dx), __fmul_rn(dy, dy)), __fmul_rn(dz, dz));
            float nd = fminf(dist[r], d);
            dist[r] = nd;
            bool tk = nd > bv;            // strict >: first-max (lowest r) kept
            bi = tk ? (t * 8 + r) : bi;
            bv = fmaxf(nd, bv);
        }
        // pack (value, min-idx-on-tie) into one max-reducible key; idx embedded
        // so keys are unique and plain u64 max is lexicographically correct
        unsigned long long k = ((unsigned long long)__float_as_uint(bv) << 32)
                             | (unsigned)(8191 - bi);
#pragma unroll
        for (int off = 32; off >= 1; off >>= 1) {
            unsigned long long o = __shfl_xor(k, off);
            k = o > k ? o : k;
        }
        if (lane == 0) partk[wave] = k;
        __syncthreads();
        if (wave == 0) {
            unsigned long long kk = (lane < 16) ? partk[lane] : 0ULL;
#pragma unroll
            for (int off = 8; off >= 1; off >>= 1) {
                unsigned long long o = __shfl_xor(kk, off);
                kk = o > kk ? o : kk;
            }
            if (lane == 0) {
                int widx = 8191 - (int)(unsigned)(kk & 0xFFFFFFFFULL);
                float wx = spx[widx], wy = spy[widx], wz = spz[widx];
                cres = make_float4(wx, wy, wz, 0.0f);
                float* rp = rep + ((size_t)b * PP + s) * 3;
                rp[0] = wx; rp[1] = wy; rp[2] = wz;
            }
        }
        __syncthreads();
        float4 c4 = cres;
        cx = c4.x; cy = c4.y; cz = c4.z;
    }
}

// ---------------------------------------------------------------------------
// Dense: fts_d = elu(fts @ W + b). One wave per row, lane = output channel.
// ---------------------------------------------------------------------------
__global__ __launch_bounds__(256) void dense_kernel(const float* __restrict__ fts,
                                                    const float* __restrict__ W,
                                                    const float* __restrict__ bias,
                                                    float* __restrict__ out) {
    const int row = blockIdx.x * 4 + (threadIdx.x >> 6);
    const int c = threadIdx.x & 63;
    float v = fts[(size_t)row * 64 + c];
    float acc = bias[c];
#pragma unroll 8
    for (int k = 0; k < 64; ++k) acc = fmaf(__shfl(v, k), W[k * 64 + c], acc);
    out[(size_t)row * 64 + c] = elu(acc);
}

// ---------------------------------------------------------------------------
// KNN: one wave per rep point; per-lane sorted top-16 of 128 candidates via
// u64 keys (flipped dist bits << 32 | idx); 16-round lex-min merge-extract.
// Exact IEEE ops, same evaluation order as reference: (a - 2b) + c.
// ---------------------------------------------------------------------------
__global__ __launch_bounds__(256) void knn_kernel(const float* __restrict__ pts,
                                                  const float* __restrict__ rep,
                                                  int* __restrict__ kidx) {
    const int wid = blockIdx.x * 4 + (threadIdx.x >> 6);
    const int lane = threadIdx.x & 63;
    const int b = wid >> 11;
    const float* pb = pts + (size_t)b * NN * 3;

    float rx = rep[(size_t)wid * 3 + 0];
    float ry = rep[(size_t)wid * 3 + 1];
    float rz = rep[(size_t)wid * 3 + 2];
    float a = __fadd_rn(__fadd_rn(__fmul_rn(rx, rx), __fmul_rn(ry, ry)), __fmul_rn(rz, rz));

    unsigned long long key[16];
#pragma unroll
    for (int s = 0; s < 16; ++s) key[s] = ~0ULL;

    for (int j = lane; j < NN; j += 64) {
        float qx = pb[j * 3 + 0], qy = pb[j * 3 + 1], qz = pb[j * 3 + 2];
        float cc = __fadd_rn(__fadd_rn(__fmul_rn(qx, qx), __fmul_rn(qy, qy)), __fmul_rn(qz, qz));
        float bs = __fadd_rn(__fadd_rn(__fmul_rn(rx, qx), __fmul_rn(ry, qy)), __fmul_rn(rz, qz));
        float d2 = __fadd_rn(__fsub_rn(a, __fmul_rn(2.0f, bs)), cc);
        unsigned long long nk = ((unsigned long long)fkey(d2) << 32) | (unsigned)j;
        if (nk < key[15]) {
            key[15] = nk;
#pragma unroll
            for (int s2 = 15; s2 > 0; --s2) {
                unsigned long long u = key[s2 - 1], w = key[s2];
                bool sw = w < u;
                key[s2 - 1] = sw ? w : u;
                key[s2] = sw ? u : w;
            }
        }
    }

    int outv = 0;
#pragma unroll 1
    for (int r = 0; r < 16; ++r) {
        unsigned long long h = key[0];
#pragma unroll
        for (int off = 1; off < 64; off <<= 1) {
            unsigned long long o = __shfl_xor(h, off);
            h = (o < h) ? o : h;
        }
        if (lane == r) outv = (int)(unsigned)(h & 0xFFFFFFFFull);
        if (key[0] == h) {  // unique winner (idx embedded in key)
#pragma unroll
            for (int s2 = 0; s2 < 15; ++s2) key[s2] = key[s2 + 1];
            key[15] = ~0ULL;
        }
    }
    if (lane < 16) kidx[(size_t)wid * 16 + lane] = outv;
}

// ---------------------------------------------------------------------------
// XConv + SepConv: one 64-thread block per rep point, all staged through LDS.
// ---------------------------------------------------------------------------
__global__ __launch_bounds__(64) void xconv_kernel(
    const float* __restrict__ pts, const float* __restrict__ rep,
    const float* __restrict__ ftsd, const int* __restrict__ kidx,
    const float* __restrict__ d1W, const float* __restrict__ d1b,
    const float* __restrict__ d2W, const float* __restrict__ d2b,
    const float* __restrict__ convW, const float* __restrict__ convb,
    const float* __restrict__ dw1W, const float* __restrict__ dw1b,
    const float* __restrict__ dw2W, const float* __restrict__ dw2b,
    const float* __restrict__ sdwW, const float* __restrict__ sdwb,
    const float* __restrict__ spwW, const float* __restrict__ spwb,
    float* __restrict__ outp) {
    const int bp = blockIdx.x;
    const int b = bp >> 11;
    const int t = threadIdx.x;

    __shared__ float pl[16][3];
    __shared__ int nidx[16];
    __shared__ float fcat[16][96];   // cols 0..31 = lift, 32..95 = gathered fts_d
    __shared__ float A1[16][32];
    __shared__ float Xm[16][17];
    __shared__ float X2[16][17];
    __shared__ float X3[16][17];
    __shared__ float fX[16][97];
    __shared__ float dsep[192];

    if (t < 16) {
        int id = kidx[(size_t)bp * 16 + t];
        nidx[t] = id;
        const float* q = pts + ((size_t)b * NN + id) * 3;
        const float* rr = rep + (size_t)bp * 3;
        pl[t][0] = q[0] - rr[0];
        pl[t][1] = q[1] - rr[1];
        pl[t][2] = q[2] - rr[2];
    }
    __syncthreads();

    // gather neighbor features (coalesced: lane = channel)
#pragma unroll
    for (int k = 0; k < 16; ++k)
        fcat[k][32 + t] = ftsd[((size_t)b * NN + nidx[k]) * 64 + t];

    // lift MLP layer 1: [16,3] @ [3,32]
#pragma unroll
    for (int r2 = 0; r2 < 8; ++r2) {
        int e = t + 64 * r2; int k = e >> 5, j = e & 31;
        float acc = d1b[j];
        acc = fmaf(pl[k][0], d1W[j], acc);
        acc = fmaf(pl[k][1], d1W[32 + j], acc);
        acc = fmaf(pl[k][2], d1W[64 + j], acc);
        A1[k][j] = elu(acc);
    }
    __syncthreads();

    // lift MLP layer 2: [16,32] @ [32,32] -> fcat cols 0..31
#pragma unroll
    for (int r2 = 0; r2 < 8; ++r2) {
        int e = t + 64 * r2; int k = e >> 5, j = e & 31;
        float acc = d2b[j];
#pragma unroll
        for (int c = 0; c < 32; ++c) acc = fmaf(A1[k][c], d2W[c * 32 + j], acc);
        fcat[k][j] = elu(acc);
    }
    __syncthreads();

    // X matrix: X[o] = elu(sum_{c,k} pl[k][c]*convW[o][c][k] + convb[o]), o=0..255
#pragma unroll
    for (int r2 = 0; r2 < 4; ++r2) {
        int o = t + 64 * r2;
        float acc = convb[o];
#pragma unroll
        for (int c = 0; c < 3; ++c)
#pragma unroll
            for (int k = 0; k < 16; ++k)
                acc = fmaf(pl[k][c], convW[(o * 3 + c) * 16 + k], acc);
        Xm[o >> 4][o & 15] = elu(acc);
    }
    __syncthreads();

    // dw1: out[j][m] = elu(sum_i Xm[i][j]*dw1W[j][m][i] + dw1b[j][m])
#pragma unroll
    for (int r2 = 0; r2 < 4; ++r2) {
        int e = t + 64 * r2; int j = e >> 4, m = e & 15;
        float acc = dw1b[e];
#pragma unroll
        for (int i = 0; i < 16; ++i) acc = fmaf(Xm[i][j], dw1W[e * 16 + i], acc);
        X2[j][m] = elu(acc);
    }
    __syncthreads();

    // dw2 (no ELU)
#pragma unroll
    for (int r2 = 0; r2 < 4; ++r2) {
        int e = t + 64 * r2; int j = e >> 4, m = e & 15;
        float acc = dw2b[e];
#pragma unroll
        for (int i = 0; i < 16; ++i) acc = fmaf(X2[i][j], dw2W[e * 16 + i], acc);
        X3[j][m] = acc;
    }
    __syncthreads();

    // fts_X[a][c] = sum_b X3[a][b] * fcat[b][c]
#pragma unroll
    for (int r2 = 0; r2 < 24; ++r2) {
        int e = t + 64 * r2; int a = e & 15, c = e >> 4;
        float acc = 0.0f;
#pragma unroll
        for (int q = 0; q < 16; ++q) acc = fmaf(X3[a][q], fcat[q][c], acc);
        fX[a][c] = acc;
    }
    __syncthreads();

    // separable depthwise: d[c][m] = sum_k fX[k][c]*sdwW[c][m][k] + sdwb[c][m]
#pragma unroll
    for (int r2 = 0; r2 < 3; ++r2) {
        int e = t + 64 * r2; int c = e >> 1;
        float acc = sdwb[e];
#pragma unroll
        for (int k = 0; k < 16; ++k) acc = fmaf(fX[k][c], sdwW[e * 16 + k], acc);
        dsep[e] = acc;
    }
    __syncthreads();

    // pointwise: out[o] = elu(sum_{c,m} d[c][m]*spwW[o][c][m] + spwb[o])
#pragma unroll
    for (int r2 = 0; r2 < 2; ++r2) {
        int o = t + 64 * r2;
        float acc = spwb[o];
#pragma unroll 16
        for (int e2 = 0; e2 < 192; ++e2) acc = fmaf(dsep[e2], spwW[o * 192 + e2], acc);
        outp[(size_t)bp * 128 + o] = elu(acc);
    }
}

extern "C" void kernel_launch(void* const* d_in, const int* in_sizes, int n_in,
                              void* d_out, int out_size, void* d_ws, size_t ws_size,
                              hipStream_t stream) {
    const float* pts    = (const float*)d_in[0];
    const float* fts    = (const float*)d_in[1];
    const float* denseW = (const float*)d_in[2];
    const float* denseb = (const float*)d_in[3];
    const float* d1W    = (const float*)d_in[4];
    const float* d1b    = (const float*)d_in[5];
    const float* d2W    = (const float*)d_in[6];
    const float* d2b    = (const float*)d_in[7];
    const float* convW  = (const float*)d_in[8];
    const float* convb  = (const float*)d_in[9];
    const float* dw1W   = (const float*)d_in[10];
    const float* dw1b   = (const float*)d_in[11];
    const float* dw2W   = (const float*)d_in[12];
    const float* dw2b   = (const float*)d_in[13];
    const float* sdwW   = (const float*)d_in[14];
    const float* sdwb   = (const float*)d_in[15];
    const float* spwW   = (const float*)d_in[16];
    const float* spwb   = (const float*)d_in[17];

    float* rep  = (float*)d_out;                       // [B,P,3]
    float* outp = (float*)d_out + (size_t)BB * PP * 3; // [B,P,128]

    float* ftsd = (float*)d_ws;                                            // B*N*64 f32
    int*   kidx = (int*)((char*)d_ws + (size_t)BB * NN * CIN * sizeof(float)); // B*P*16 i32

    dense_kernel<<<BB * NN / 4, 256, 0, stream>>>(fts, denseW, denseb, ftsd);
    fps_kernel<<<BB, 1024, 0, stream>>>(pts, rep);
    knn_kernel<<<BB * PP / 4, 256, 0, stream>>>(pts, rep, kidx);
    xconv_kernel<<<BB * PP, 64, 0, stream>>>(pts, rep, ftsd, kidx,
                                             d1W, d1b, d2W, d2b, convW, convb,
                                             dw1W, dw1b, dw2W, dw2b,
                                             sdwW, sdwb, spwW, spwb, outp);
}

// Round 3
// 2580.997 us; speedup vs baseline: 2.3816x; 1.1602x over previous
//
#include <hip/hip_runtime.h>

#define BB 4
#define NN 8192
#define PP 2048
#define KNB 16
#define CIN 64
#define COUT 128

__device__ __forceinline__ float elu(float x) { return x > 0.0f ? x : expm1f(x); }

// monotone float->uint key (handles negative floats from cancellation)
__device__ __forceinline__ unsigned fkey(float d) {
    unsigned u = __float_as_uint(d);
    unsigned m = (unsigned)((int)u >> 31);
    return u ^ (m | 0x80000000u);
}

// ---------------------------------------------------------------------------
// FPS v3: one block per batch, 512 threads, 16 points/thread in registers,
// all points mirrored in LDS for winner-coordinate lookup.
// ONE barrier per round: per-wave partial keys are double-buffered, and all
// threads scan the 8 partials themselves (broadcast LDS reads) instead of a
// wave0-only reduce + second barrier.
// Packed u64 key (dist_bits<<32 | (8191-idx)): plain u64 max reduce is
// lexicographically (max dist, min idx) == jnp.argmax first-max semantics.
// Exact IEEE ops (no FMA) in distance path to match reference selection.
// ---------------------------------------------------------------------------
__global__ __launch_bounds__(512) void fps_kernel(const float* __restrict__ pts,
                                                  float* __restrict__ rep) {
    const int b = blockIdx.x;
    const int t = threadIdx.x;
    const int lane = t & 63, wave = t >> 6;   // 8 waves

    __shared__ float spx[NN];
    __shared__ float spy[NN];
    __shared__ float spz[NN];
    __shared__ unsigned long long partk[2][8];

    const float* pb = pts + (size_t)b * NN * 3;
    for (int i = t; i < NN; i += 512) {
        spx[i] = pb[3 * i + 0];
        spy[i] = pb[3 * i + 1];
        spz[i] = pb[3 * i + 2];
    }
    __syncthreads();

    float px[16], py[16], pz[16], dist[16];
#pragma unroll
    for (int r = 0; r < 16; ++r) {
        px[r] = spx[t * 16 + r];
        py[r] = spy[t * 16 + r];
        pz[r] = spz[t * 16 + r];
        dist[r] = 1e10f;
    }

    float cx = spx[0], cy = spy[0], cz = spz[0];
    if (t == 0) {
        rep[(size_t)b * PP * 3 + 0] = cx;
        rep[(size_t)b * PP * 3 + 1] = cy;
        rep[(size_t)b * PP * 3 + 2] = cz;
    }

    int buf = 0;
    for (int s = 1; s < PP; ++s) {
        float bv = -1.0f; int bi = 0;
#pragma unroll
        for (int r = 0; r < 16; ++r) {
            float dx = __fsub_rn(px[r], cx);
            float dy = __fsub_rn(py[r], cy);
            float dz = __fsub_rn(pz[r], cz);
            float d = __fadd_rn(__fadd_rn(__fmul_rn(dx, dx), __fmul_rn(dy, dy)), __fmul_rn(dz, dz));
            float nd = fminf(dist[r], d);
            dist[r] = nd;
            bool tk = nd > bv;            // strict >: first-max (lowest r) kept
            bi = tk ? (t * 16 + r) : bi;
            bv = fmaxf(nd, bv);
        }
        unsigned long long k = ((unsigned long long)__float_as_uint(bv) << 32)
                             | (unsigned)(8191 - bi);
#pragma unroll
        for (int off = 32; off >= 1; off >>= 1) {
            unsigned long long o = __shfl_xor(k, off);
            k = o > k ? o : k;
        }
        if (lane == 0) partk[buf][wave] = k;
        __syncthreads();
        // all threads scan the 8 partials (broadcast reads) -> winner everywhere
        unsigned long long kk = partk[buf][0];
#pragma unroll
        for (int q = 1; q < 8; ++q) {
            unsigned long long c = partk[buf][q];
            kk = c > kk ? c : kk;
        }
        int widx = 8191 - (int)(unsigned)(kk & 0xFFFFFFFFULL);
        cx = spx[widx]; cy = spy[widx]; cz = spz[widx];
        if (t == 0) {
            float* rp = rep + ((size_t)b * PP + s) * 3;
            rp[0] = cx; rp[1] = cy; rp[2] = cz;
        }
        buf ^= 1;
    }
}

// ---------------------------------------------------------------------------
// Dense: fts_d = elu(fts @ W + b). One wave per row, lane = output channel.
// ---------------------------------------------------------------------------
__global__ __launch_bounds__(256) void dense_kernel(const float* __restrict__ fts,
                                                    const float* __restrict__ W,
                                                    const float* __restrict__ bias,
                                                    float* __restrict__ out) {
    const int row = blockIdx.x * 4 + (threadIdx.x >> 6);
    const int c = threadIdx.x & 63;
    float v = fts[(size_t)row * 64 + c];
    float acc = bias[c];
#pragma unroll 8
    for (int k = 0; k < 64; ++k) acc = fmaf(__shfl(v, k), W[k * 64 + c], acc);
    out[(size_t)row * 64 + c] = elu(acc);
}

// ---------------------------------------------------------------------------
// KNN: one wave per rep point; per-lane sorted top-16 of 128 candidates via
// u64 keys (flipped dist bits << 32 | idx); 16-round lex-min merge-extract.
// Exact IEEE ops, same evaluation order as reference: (a - 2b) + c.
// ---------------------------------------------------------------------------
__global__ __launch_bounds__(256) void knn_kernel(const float* __restrict__ pts,
                                                  const float* __restrict__ rep,
                                                  int* __restrict__ kidx) {
    const int wid = blockIdx.x * 4 + (threadIdx.x >> 6);
    const int lane = threadIdx.x & 63;
    const int b = wid >> 11;
    const float* pb = pts + (size_t)b * NN * 3;

    float rx = rep[(size_t)wid * 3 + 0];
    float ry = rep[(size_t)wid * 3 + 1];
    float rz = rep[(size_t)wid * 3 + 2];
    float a = __fadd_rn(__fadd_rn(__fmul_rn(rx, rx), __fmul_rn(ry, ry)), __fmul_rn(rz, rz));

    unsigned long long key[16];
#pragma unroll
    for (int s = 0; s < 16; ++s) key[s] = ~0ULL;

    for (int j = lane; j < NN; j += 64) {
        float qx = pb[j * 3 + 0], qy = pb[j * 3 + 1], qz = pb[j * 3 + 2];
        float cc = __fadd_rn(__fadd_rn(__fmul_rn(qx, qx), __fmul_rn(qy, qy)), __fmul_rn(qz, qz));
        float bs = __fadd_rn(__fadd_rn(__fmul_rn(rx, qx), __fmul_rn(ry, qy)), __fmul_rn(rz, qz));
        float d2 = __fadd_rn(__fsub_rn(a, __fmul_rn(2.0f, bs)), cc);
        unsigned long long nk = ((unsigned long long)fkey(d2) << 32) | (unsigned)j;
        if (nk < key[15]) {
            key[15] = nk;
#pragma unroll
            for (int s2 = 15; s2 > 0; --s2) {
                unsigned long long u = key[s2 - 1], w = key[s2];
                bool sw = w < u;
                key[s2 - 1] = sw ? w : u;
                key[s2] = sw ? u : w;
            }
        }
    }

    int outv = 0;
#pragma unroll 1
    for (int r = 0; r < 16; ++r) {
        unsigned long long h = key[0];
#pragma unroll
        for (int off = 1; off < 64; off <<= 1) {
            unsigned long long o = __shfl_xor(h, off);
            h = (o < h) ? o : h;
        }
        if (lane == r) outv = (int)(unsigned)(h & 0xFFFFFFFFull);
        if (key[0] == h) {  // unique winner (idx embedded in key)
#pragma unroll
            for (int s2 = 0; s2 < 15; ++s2) key[s2] = key[s2 + 1];
            key[15] = ~0ULL;
        }
    }
    if (lane < 16) kidx[(size_t)wid * 16 + lane] = outv;
}

// ---------------------------------------------------------------------------
// XConv + SepConv: one 64-thread block per rep point, all staged through LDS.
// ---------------------------------------------------------------------------
__global__ __launch_bounds__(64) void xconv_kernel(
    const float* __restrict__ pts, const float* __restrict__ rep,
    const float* __restrict__ ftsd, const int* __restrict__ kidx,
    const float* __restrict__ d1W, const float* __restrict__ d1b,
    const float* __restrict__ d2W, const float* __restrict__ d2b,
    const float* __restrict__ convW, const float* __restrict__ convb,
    const float* __restrict__ dw1W, const float* __restrict__ dw1b,
    const float* __restrict__ dw2W, const float* __restrict__ dw2b,
    const float* __restrict__ sdwW, const float* __restrict__ sdwb,
    const float* __restrict__ spwW, const float* __restrict__ spwb,
    float* __restrict__ outp) {
    const int bp = blockIdx.x;
    const int b = bp >> 11;
    const int t = threadIdx.x;

    __shared__ float pl[16][3];
    __shared__ int nidx[16];
    __shared__ float fcat[16][96];   // cols 0..31 = lift, 32..95 = gathered fts_d
    __shared__ float A1[16][32];
    __shared__ float Xm[16][17];
    __shared__ float X2[16][17];
    __shared__ float X3[16][17];
    __shared__ float fX[16][97];
    __shared__ float dsep[192];

    if (t < 16) {
        int id = kidx[(size_t)bp * 16 + t];
        nidx[t] = id;
        const float* q = pts + ((size_t)b * NN + id) * 3;
        const float* rr = rep + (size_t)bp * 3;
        pl[t][0] = q[0] - rr[0];
        pl[t][1] = q[1] - rr[1];
        pl[t][2] = q[2] - rr[2];
    }
    __syncthreads();

    // gather neighbor features (coalesced: lane = channel)
#pragma unroll
    for (int k = 0; k < 16; ++k)
        fcat[k][32 + t] = ftsd[((size_t)b * NN + nidx[k]) * 64 + t];

    // lift MLP layer 1: [16,3] @ [3,32]
#pragma unroll
    for (int r2 = 0; r2 < 8; ++r2) {
        int e = t + 64 * r2; int k = e >> 5, j = e & 31;
        float acc = d1b[j];
        acc = fmaf(pl[k][0], d1W[j], acc);
        acc = fmaf(pl[k][1], d1W[32 + j], acc);
        acc = fmaf(pl[k][2], d1W[64 + j], acc);
        A1[k][j] = elu(acc);
    }
    __syncthreads();

    // lift MLP layer 2: [16,32] @ [32,32] -> fcat cols 0..31
#pragma unroll
    for (int r2 = 0; r2 < 8; ++r2) {
        int e = t + 64 * r2; int k = e >> 5, j = e & 31;
        float acc = d2b[j];
#pragma unroll
        for (int c = 0; c < 32; ++c) acc = fmaf(A1[k][c], d2W[c * 32 + j], acc);
        fcat[k][j] = elu(acc);
    }
    __syncthreads();

    // X matrix: X[o] = elu(sum_{c,k} pl[k][c]*convW[o][c][k] + convb[o]), o=0..255
#pragma unroll
    for (int r2 = 0; r2 < 4; ++r2) {
        int o = t + 64 * r2;
        float acc = convb[o];
#pragma unroll
        for (int c = 0; c < 3; ++c)
#pragma unroll
            for (int k = 0; k < 16; ++k)
                acc = fmaf(pl[k][c], convW[(o * 3 + c) * 16 + k], acc);
        Xm[o >> 4][o & 15] = elu(acc);
    }
    __syncthreads();

    // dw1: out[j][m] = elu(sum_i Xm[i][j]*dw1W[j][m][i] + dw1b[j][m])
#pragma unroll
    for (int r2 = 0; r2 < 4; ++r2) {
        int e = t + 64 * r2; int j = e >> 4, m = e & 15;
        float acc = dw1b[e];
#pragma unroll
        for (int i = 0; i < 16; ++i) acc = fmaf(Xm[i][j], dw1W[e * 16 + i], acc);
        X2[j][m] = elu(acc);
    }
    __syncthreads();

    // dw2 (no ELU)
#pragma unroll
    for (int r2 = 0; r2 < 4; ++r2) {
        int e = t + 64 * r2; int j = e >> 4, m = e & 15;
        float acc = dw2b[e];
#pragma unroll
        for (int i = 0; i < 16; ++i) acc = fmaf(X2[i][j], dw2W[e * 16 + i], acc);
        X3[j][m] = acc;
    }
    __syncthreads();

    // fts_X[a][c] = sum_b X3[a][b] * fcat[b][c]
#pragma unroll
    for (int r2 = 0; r2 < 24; ++r2) {
        int e = t + 64 * r2; int a = e & 15, c = e >> 4;
        float acc = 0.0f;
#pragma unroll
        for (int q = 0; q < 16; ++q) acc = fmaf(X3[a][q], fcat[q][c], acc);
        fX[a][c] = acc;
    }
    __syncthreads();

    // separable depthwise: d[c][m] = sum_k fX[k][c]*sdwW[c][m][k] + sdwb[c][m]
#pragma unroll
    for (int r2 = 0; r2 < 3; ++r2) {
        int e = t + 64 * r2; int c = e >> 1;
        float acc = sdwb[e];
#pragma unroll
        for (int k = 0; k < 16; ++k) acc = fmaf(fX[k][c], sdwW[e * 16 + k], acc);
        dsep[e] = acc;
    }
    __syncthreads();

    // pointwise: out[o] = elu(sum_{c,m} d[c][m]*spwW[o][c][m] + spwb[o])
#pragma unroll
    for (int r2 = 0; r2 < 2; ++r2) {
        int o = t + 64 * r2;
        float acc = spwb[o];
#pragma unroll 16
        for (int e2 = 0; e2 < 192; ++e2) acc = fmaf(dsep[e2], spwW[o * 192 + e2], acc);
        outp[(size_t)bp * 128 + o] = elu(acc);
    }
}

extern "C" void kernel_launch(void* const* d_in, const int* in_sizes, int n_in,
                              void* d_out, int out_size, void* d_ws, size_t ws_size,
                              hipStream_t stream) {
    const float* pts    = (const float*)d_in[0];
    const float* fts    = (const float*)d_in[1];
    const float* denseW = (const float*)d_in[2];
    const float* denseb = (const float*)d_in[3];
    const float* d1W    = (const float*)d_in[4];
    const float* d1b    = (const float*)d_in[5];
    const float* d2W    = (const float*)d_in[6];
    const float* d2b    = (const float*)d_in[7];
    const float* convW  = (const float*)d_in[8];
    const float* convb  = (const float*)d_in[9];
    const float* dw1W   = (const float*)d_in[10];
    const float* dw1b   = (const float*)d_in[11];
    const float* dw2W   = (const float*)d_in[12];
    const float* dw2b   = (const float*)d_in[13];
    const float* sdwW   = (const float*)d_in[14];
    const float* sdwb   = (const float*)d_in[15];
    const float* spwW   = (const float*)d_in[16];
    const float* spwb   = (const float*)d_in[17];

    float* rep  = (float*)d_out;                       // [B,P,3]
    float* outp = (float*)d_out + (size_t)BB * PP * 3; // [B,P,128]

    float* ftsd = (float*)d_ws;                                            // B*N*64 f32
    int*   kidx = (int*)((char*)d_ws + (size_t)BB * NN * CIN * sizeof(float)); // B*P*16 i32

    dense_kernel<<<BB * NN / 4, 256, 0, stream>>>(fts, denseW, denseb, ftsd);
    fps_kernel<<<BB, 512, 0, stream>>>(pts, rep);
    knn_kernel<<<BB * PP / 4, 256, 0, stream>>>(pts, rep, kidx);
    xconv_kernel<<<BB * PP, 64, 0, stream>>>(pts, rep, ftsd, kidx,
                                             d1W, d1b, d2W, d2b, convW, convb,
                                             dw1W, dw1b, dw2W, dw2b,
                                             sdwW, sdwb, spwW, spwb, outp);
}